// Round 14
// baseline (183.776 us; speedup 1.0000x reference)
//
#include <hip/hip_runtime.h>
#include <hip/hip_bf16.h>
#include <cstdint>
#include <cstddef>

typedef _Float16 f16;
typedef _Float16 f16x8 __attribute__((ext_vector_type(8)));
typedef _Float16 f16x4 __attribute__((ext_vector_type(4)));
typedef float    f32x4 __attribute__((ext_vector_type(4)));
typedef unsigned int u32;

#define B_SZ   8
#define NPOS   3136      // 56*56
#define CIN    256
#define CI     128       // C_INTER
#define CO     256
#define MTOT   (B_SZ*NPOS)   // 25088
#define NT     49            // KV tiles of 64
#define NQT    13            // q-tiles of 256 (13*256 = 3328 >= 3136)
#define L2E    1.44269504f

union HPack { f16 h[2]; u32 u; };
union HVec8 { u32 u[4]; f16x8 v; };

// async global->LDS, 16B per lane; LDS dest = wave-uniform base + lane*16
__device__ __forceinline__ void async16(const f16* g, f16* l) {
    __builtin_amdgcn_global_load_lds((const __attribute__((address_space(1))) void*)g,
                                     (__attribute__((address_space(3))) void*)l, 16, 0, 0);
}

// ---------------------------------------------------------------------------
// Kernel 0: weight prep — transpose + fp32->fp16
// ---------------------------------------------------------------------------
__global__ void prep_weights(const float* __restrict__ wt, const float* __restrict__ wp,
                             const float* __restrict__ wg, const float* __restrict__ wo,
                             f16* __restrict__ wprojT, f16* __restrict__ woutT) {
    int o = blockIdx.x;
    int k = threadIdx.x;
    if (o < 384) {
        const float* w = (o < 128) ? wt : (o < 256) ? wp : wg;
        int d = o & 127;
        wprojT[o * 256 + k] = (f16)w[k * 128 + d];
    } else {
        int oo = o - 384;           // 0..255
        if (k < 128) woutT[oo * 128 + k] = (f16)wo[k * 256 + oo];
    }
}

// ---------------------------------------------------------------------------
// Kernel 1: fused projection GEMM.  grid (392, 2); theta pre-scaled by
//   log2(e); g^T via swapped mfma; DOUBLE bounce buffer -> 1 barrier/col-tile.
// ---------------------------------------------------------------------------
__launch_bounds__(256)
__global__ void proj_gemm(const float* __restrict__ x, const f16* __restrict__ wprojT,
                          const float* __restrict__ bth, const float* __restrict__ bph,
                          const float* __restrict__ bgg,
                          f16* __restrict__ theta, f16* __restrict__ phi,
                          f16* __restrict__ gt) {
    const int mt  = blockIdx.x;          // 0..391
    const int cy  = blockIdx.y;          // 0..1
    const int m0  = mt * 64;
    const int b   = mt / NT;
    const int n0  = (mt % NT) * 64;
    const int tid = threadIdx.x;
    const int w   = tid >> 6;
    const int l   = tid & 63;
    const int lrow = l & 15;
    const int lk8  = (l >> 4) * 8;

    __shared__ alignas(16) f16 At[64 * 256];
    __shared__ alignas(16) f16 Bo[2][64 * 72];

    #pragma unroll
    for (int i = 0; i < 16; ++i) {
        int c   = tid + 256 * i;
        int row = c >> 6;
        int col = (c & 63) * 4;
        f32x4 v = *reinterpret_cast<const f32x4*>(&x[(size_t)(m0 + row) * CIN + col]);
        f16x4 t;
        t[0] = (f16)v[0]; t[1] = (f16)v[1]; t[2] = (f16)v[2]; t[3] = (f16)v[3];
        *reinterpret_cast<f16x4*>(&At[row * 256 + (col ^ ((row & 7) << 3))]) = t;
    }
    __syncthreads();

    const int arow = w * 16 + lrow;
    f16x8 af[8];
    #pragma unroll
    for (int kt = 0; kt < 8; ++kt) {
        int kk = kt * 32 + lk8;
        af[kt] = *reinterpret_cast<const f16x8*>(&At[arow * 256 + (kk ^ ((arow & 7) << 3))]);
    }

    for (int cc = 0; cc < 3; ++cc) {
        const int ct = cy * 3 + cc;
        f16* BO = Bo[cc & 1];
        f32x4 acc[4];
        #pragma unroll
        for (int c0 = 0; c0 < 4; ++c0) acc[c0] = (f32x4){0.f, 0.f, 0.f, 0.f};
        const int c0base = ct * 64;
        const bool is_g = (ct >= 4);
        #pragma unroll
        for (int kt = 0; kt < 8; ++kt) {
            int kk = kt * 32 + lk8;
            #pragma unroll
            for (int c0 = 0; c0 < 4; ++c0) {
                int col = c0base + c0 * 16 + lrow;
                f16x8 bb = *reinterpret_cast<const f16x8*>(&wprojT[col * 256 + kk]);
                if (is_g)
                    acc[c0] = __builtin_amdgcn_mfma_f32_16x16x32_f16(bb, af[kt], acc[c0], 0, 0, 0);
                else
                    acc[c0] = __builtin_amdgcn_mfma_f32_16x16x32_f16(af[kt], bb, acc[c0], 0, 0, 0);
            }
        }
        if (!is_g) {
            const float* bv = (ct < 2) ? bth : bph;
            #pragma unroll
            for (int c0 = 0; c0 < 4; ++c0) {
                int d = ((c0base + c0 * 16 + lrow) & 127);
                float bias = bv[d];
                #pragma unroll
                for (int j = 0; j < 4; ++j) {
                    int r = w * 16 + (l >> 4) * 4 + j;
                    float v = acc[c0][j] + bias;
                    if (ct < 2) v *= L2E;
                    BO[r * 72 + c0 * 16 + lrow] = (f16)v;
                }
            }
        } else {
            #pragma unroll
            for (int c0 = 0; c0 < 4; ++c0) {
                #pragma unroll
                for (int j = 0; j < 4; ++j) {
                    int dsub = c0 * 16 + (l >> 4) * 4 + j;
                    int d    = (ct - 4) * 64 + dsub;
                    BO[dsub * 72 + w * 16 + lrow] = (f16)(acc[c0][j] + bgg[d]);
                }
            }
        }
        __syncthreads();   // writes visible; next ct writes the OTHER buffer
        {
            int r   = tid >> 2;
            int cb  = (tid & 3) * 16;
            f16x8 v0 = *reinterpret_cast<const f16x8*>(&BO[r * 72 + cb]);
            f16x8 v1 = *reinterpret_cast<const f16x8*>(&BO[r * 72 + cb + 8]);
            if (!is_g) {
                f16* dst = (ct < 2) ? theta : phi;
                int dbase = (ct & 1) * 64;
                size_t off = ((size_t)b * NPOS + n0 + r) * CI + dbase + cb;
                *reinterpret_cast<f16x8*>(&dst[off])     = v0;
                *reinterpret_cast<f16x8*>(&dst[off + 8]) = v1;
            } else {
                int dglob = (ct - 4) * 64 + r;
                size_t off = ((size_t)b * CI + dglob) * NPOS + n0 + cb;
                *reinterpret_cast<f16x8*>(&gt[off])     = v0;
                *reinterpret_cast<f16x8*>(&gt[off + 8]) = v1;
            }
        }
    }
}

// ---------------------------------------------------------------------------
// Kernel 2: flash attention, KV-split. 1024 thr (16 waves), QBLK=256 (16 q
//   rows/wave — per-wave code identical to r12), KVBLK=64, dbuf K/V, 1
//   barrier/tile. 64 KB LDS -> 2 blocks/CU = 32 waves/CU (HW max).
//   gload_lds staging: linear LDS dest, inverse-swizzled per-lane source;
//   t+1 loads issued at loop top, land under compute. Swapped QK^T -> S^T in
//   regs; in-register softmax; P repacked to PV A-fragments via shfl.
// ---------------------------------------------------------------------------
__launch_bounds__(1024)
__global__ void attn_partial(const f16* __restrict__ theta, const f16* __restrict__ phi,
                             const f16* __restrict__ gt, f16* __restrict__ Opart,
                             float2* __restrict__ ml, int nsplit, int do_ml) {
    const int b   = blockIdx.x;   // 0..7  (XCD-pinned)
    const int qt  = blockIdx.y;   // 0..12
    const int s   = blockIdx.z;   // 0..nsplit-1
    const int t0  = (NT * s) / nsplit;
    const int t1  = (NT * (s + 1)) / nsplit;
    const int tid = threadIdx.x;
    const int w   = tid >> 6;     // 0..15
    const int l   = tid & 63;
    const int lrow = l & 15;
    const int lk8  = (l >> 4) * 8;

    __shared__ alignas(16) f16 Kt[2][64 * 128];  // 32 KB (swizzled via source)
    __shared__ alignas(16) f16 Vt[2][128 * 64];  // 32 KB

    const f16* thB = theta + (size_t)b * NPOS * CI;
    const f16* phB = phi   + (size_t)b * NPOS * CI;
    const f16* gtB = gt    + (size_t)b * CI * NPOS;

    const int q0  = qt * 256 + w * 16;
    const int qld = min(q0 + lrow, NPOS - 1);

    // Q fragments (B-operand for swapped QK^T)
    f16x8 aq[4];
    #pragma unroll
    for (int kt = 0; kt < 4; ++kt)
        aq[kt] = *reinterpret_cast<const f16x8*>(&thB[(size_t)qld * CI + kt * 32 + lk8]);

    // ---- gload_lds staging geometry: 1024 chunks of 16B, 1 per thread ----
    const int kr  = tid >> 4, kcs = ((tid & 15) ^ (kr & 7)) * 8;  // K: 64r x 16ch
    const int vr  = tid >> 3, vcs = ((tid & 7) ^ (vr & 7)) * 8;   // V: 128r x 8ch
    const int lbase = (w * 64) * 8;                               // f16 units

    f32x4 o[8];
    #pragma unroll
    for (int d0 = 0; d0 < 8; ++d0) o[d0] = (f32x4){0.f, 0.f, 0.f, 0.f};
    float mq = -1e30f;          // running max for q = l&15 (log2 domain)
    float lq = 0.f;             // running denominator for q = l&15

    // P-redistribution lane constants
    const int src0 = ((l & 16) ? 32 : 0) + lrow;   // 32*(g'&1) + q
    const int src1 = src0 + 16;
    const bool selhi = (l >= 32);

    // prologue: stage tile t0 into buf 0
    {
        int kv0 = t0 * 64;
        async16(phB + (size_t)(kv0 + kr) * CI + kcs, &Kt[0][lbase]);
        async16(gtB + (size_t)vr * NPOS + kv0 + vcs, &Vt[0][lbase]);
    }
    __syncthreads();
    int cur = 0;

    for (int t = t0; t < t1; ++t) {
        // ---- issue t+1 staging into buf[cur^1]; lands under compute ----
        if (t + 1 < t1) {
            int nv0 = (t + 1) * 64;
            async16(phB + (size_t)(nv0 + kr) * CI + kcs, &Kt[cur ^ 1][lbase]);
            async16(gtB + (size_t)vr * NPOS + nv0 + vcs, &Vt[cur ^ 1][lbase]);
        }
        const f16* KT = Kt[cur];
        const f16* VT = Vt[cur];

        // ---- S^T = K Q^T (swapped): q=l&15, kv=c0*16+(l>>4)*4+j ----
        f32x4 sr[4];
        #pragma unroll
        for (int c0 = 0; c0 < 4; ++c0) sr[c0] = (f32x4){0.f, 0.f, 0.f, 0.f};
        __builtin_amdgcn_s_setprio(1);
        #pragma unroll
        for (int kt = 0; kt < 4; ++kt) {
            #pragma unroll
            for (int c0 = 0; c0 < 4; ++c0) {
                int krow = c0 * 16 + lrow;
                f16x8 bk = *reinterpret_cast<const f16x8*>(
                    &KT[krow * 128 + ((kt * 32 + lk8) ^ ((krow & 7) << 3))]);
                sr[c0] = __builtin_amdgcn_mfma_f32_16x16x32_f16(bk, aq[kt], sr[c0], 0, 0, 0);
            }
        }
        __builtin_amdgcn_s_setprio(0);

        // ---- in-register online softmax (lazy max, deferred cross-lane sum) ----
        float m01 = fmaxf(fmaxf(sr[0][0], sr[0][1]), fmaxf(sr[0][2], sr[0][3]));
        float m23 = fmaxf(fmaxf(sr[1][0], sr[1][1]), fmaxf(sr[1][2], sr[1][3]));
        float m45 = fmaxf(fmaxf(sr[2][0], sr[2][1]), fmaxf(sr[2][2], sr[2][3]));
        float m67 = fmaxf(fmaxf(sr[3][0], sr[3][1]), fmaxf(sr[3][2], sr[3][3]));
        float rml = fmaxf(fmaxf(m01, m23), fmaxf(m45, m67));

        if (__any(rml > mq + 8.0f)) {
            float rm = fmaxf(rml, __shfl_xor(rml, 16));
            rm = fmaxf(rm, __shfl_xor(rm, 32));
            float mnew  = fmaxf(mq, rm);
            float scale = __builtin_amdgcn_exp2f(mq - mnew);
            mq = mnew;
            lq *= scale;
            float sc0 = __shfl(scale, (l >> 4) * 4 + 0);
            float sc1 = __shfl(scale, (l >> 4) * 4 + 1);
            float sc2 = __shfl(scale, (l >> 4) * 4 + 2);
            float sc3 = __shfl(scale, (l >> 4) * 4 + 3);
            #pragma unroll
            for (int d0 = 0; d0 < 8; ++d0) {
                o[d0][0] *= sc0; o[d0][1] *= sc1; o[d0][2] *= sc2; o[d0][3] *= sc3;
            }
        }

        float p[4][4];
        #pragma unroll
        for (int c0 = 0; c0 < 4; ++c0)
            #pragma unroll
            for (int j = 0; j < 4; ++j)
                p[c0][j] = __builtin_amdgcn_exp2f(sr[c0][j] - mq);
        {
            float s0 = (p[0][0] + p[0][1]) + (p[0][2] + p[0][3]);
            float s1 = (p[1][0] + p[1][1]) + (p[1][2] + p[1][3]);
            float s2 = (p[2][0] + p[2][1]) + (p[2][2] + p[2][3]);
            float s3 = (p[3][0] + p[3][1]) + (p[3][2] + p[3][3]);
            lq += (s0 + s1) + (s2 + s3);
        }

        // ---- pack P to f16 pairs ----
        u32 wlo[4], whi[4];
        #pragma unroll
        for (int c0 = 0; c0 < 4; ++c0) {
            HPack a, bpk;
            a.h[0]   = (f16)p[c0][0]; a.h[1]   = (f16)p[c0][1];
            bpk.h[0] = (f16)p[c0][2]; bpk.h[1] = (f16)p[c0][3];
            wlo[c0] = a.u; whi[c0] = bpk.u;
        }

        // ---- redistribute to PV A-fragments (registers only) ----
        HVec8 pa0, pa1;
        {
            u32 aL0 = (u32)__shfl((int)wlo[0], src0), aH0 = (u32)__shfl((int)wlo[1], src0);
            u32 aL1 = (u32)__shfl((int)whi[0], src0), aH1 = (u32)__shfl((int)whi[1], src0);
            u32 bL0 = (u32)__shfl((int)wlo[0], src1), bH0 = (u32)__shfl((int)wlo[1], src1);
            u32 bL1 = (u32)__shfl((int)whi[0], src1), bH1 = (u32)__shfl((int)whi[1], src1);
            pa0.u[0] = selhi ? aH0 : aL0;
            pa0.u[1] = selhi ? aH1 : aL1;
            pa0.u[2] = selhi ? bH0 : bL0;
            pa0.u[3] = selhi ? bH1 : bL1;
        }
        {
            u32 aL0 = (u32)__shfl((int)wlo[2], src0), aH0 = (u32)__shfl((int)wlo[3], src0);
            u32 aL1 = (u32)__shfl((int)whi[2], src0), aH1 = (u32)__shfl((int)whi[3], src0);
            u32 bL0 = (u32)__shfl((int)wlo[2], src1), bH0 = (u32)__shfl((int)wlo[3], src1);
            u32 bL1 = (u32)__shfl((int)whi[2], src1), bH1 = (u32)__shfl((int)whi[3], src1);
            pa1.u[0] = selhi ? aH0 : aL0;
            pa1.u[1] = selhi ? aH1 : aL1;
            pa1.u[2] = selhi ? bH0 : bL0;
            pa1.u[3] = selhi ? bH1 : bL1;
        }

        // ---- O += P V (A from registers, B from LDS) ----
        __builtin_amdgcn_s_setprio(1);
        #pragma unroll
        for (int d0 = 0; d0 < 8; ++d0) {
            int vrow = d0 * 16 + lrow;
            f16x8 bv0 = *reinterpret_cast<const f16x8*>(
                &VT[vrow * 64 + ((lk8) ^ ((vrow & 7) << 3))]);
            f16x8 bv1 = *reinterpret_cast<const f16x8*>(
                &VT[vrow * 64 + ((32 + lk8) ^ ((vrow & 7) << 3))]);
            o[d0] = __builtin_amdgcn_mfma_f32_16x16x32_f16(pa0.v, bv0, o[d0], 0, 0, 0);
            o[d0] = __builtin_amdgcn_mfma_f32_16x16x32_f16(pa1.v, bv1, o[d0], 0, 0, 0);
        }
        __builtin_amdgcn_s_setprio(0);

        __syncthreads();   // drains vmcnt (t+1 loads done) + barrier -> visible
        cur ^= 1;
    }

    // ---- epilogue ----
    lq += __shfl_xor(lq, 16);
    lq += __shfl_xor(lq, 32);
    float inv = 1.f / lq;
    float invj[4];
    #pragma unroll
    for (int j = 0; j < 4; ++j)
        invj[j] = __shfl(inv, (l >> 4) * 4 + j);

    #pragma unroll
    for (int j = 0; j < 4; ++j) {
        int qrow = q0 + (l >> 4) * 4 + j;
        if (qrow < NPOS) {
            size_t grow = (size_t)b * NPOS + qrow;
            #pragma unroll
            for (int d0 = 0; d0 < 8; ++d0) {
                int d = d0 * 16 + lrow;
                Opart[((size_t)s * MTOT + grow) * CI + d] = (f16)(o[d0][j] * invj[j]);
            }
        }
    }
    if (do_ml && l < 16 && q0 + l < NPOS) {
        float2 v; v.x = mq; v.y = lq;
        ml[(size_t)s * MTOT + (size_t)b * NPOS + q0 + l] = v;
    }
}

// ---------------------------------------------------------------------------
// Kernel 3: fused merge + out projection (runtime-nsplit merge loop).
//   aq = (sum_s wgt_s O_s) / sum_s wgt_s, then out = x + aq @ w_out + b_out.
// ---------------------------------------------------------------------------
__launch_bounds__(256)
__global__ void out_proj(const f16* __restrict__ Opart, const float2* __restrict__ ml,
                         int nsplit, const f16* __restrict__ woutT,
                         const float* __restrict__ bout, const float* __restrict__ x,
                         float* __restrict__ out) {
    const int mt  = blockIdx.x;
    const int ch  = blockIdx.y;
    const int tid = threadIdx.x;
    const int w   = tid >> 6;
    const int l   = tid & 63;
    const int lrow = l & 15;
    const int lk8  = (l >> 4) * 8;
    const int m0   = mt * 64;
    const int row  = m0 + w * 16 + lrow;

    __shared__ alignas(16) float OB[64 * 132];

    f16x8 aq[4];
    if (nsplit > 1) {
        float wgt[8];
        float M = -1e30f;
        for (int s2 = 0; s2 < nsplit; ++s2)
            M = fmaxf(M, ml[(size_t)s2 * MTOT + row].x);
        float L = 0.f;
        for (int s2 = 0; s2 < nsplit; ++s2) {
            float2 v = ml[(size_t)s2 * MTOT + row];
            float wv = v.y * __builtin_amdgcn_exp2f(v.x - M);
            wgt[s2] = wv; L += wv;
        }
        float invL = 1.f / L;
        #pragma unroll
        for (int kt = 0; kt < 4; ++kt) {
            float acc8[8];
            #pragma unroll
            for (int j = 0; j < 8; ++j) acc8[j] = 0.f;
            for (int s2 = 0; s2 < nsplit; ++s2) {
                f16x8 v = *reinterpret_cast<const f16x8*>(
                    &Opart[((size_t)s2 * MTOT + row) * CI + kt * 32 + lk8]);
                float wv = wgt[s2];
                #pragma unroll
                for (int j = 0; j < 8; ++j) acc8[j] += wv * (float)v[j];
            }
            f16x8 q;
            #pragma unroll
            for (int j = 0; j < 8; ++j) q[j] = (f16)(acc8[j] * invL);
            aq[kt] = q;
        }
    } else {
        #pragma unroll
        for (int kt = 0; kt < 4; ++kt)
            aq[kt] = *reinterpret_cast<const f16x8*>(&Opart[(size_t)row * CI + kt * 32 + lk8]);
    }

    #pragma unroll
    for (int cc = 0; cc < 2; ++cc) {
        const int cbase = cc * 64;
        f32x4 acc[4];
        #pragma unroll
        for (int c0 = 0; c0 < 4; ++c0) acc[c0] = (f32x4){0.f, 0.f, 0.f, 0.f};
        #pragma unroll
        for (int kt = 0; kt < 4; ++kt) {
            #pragma unroll
            for (int c0 = 0; c0 < 4; ++c0) {
                int oc = ch * 128 + cbase + c0 * 16 + lrow;
                f16x8 bb = *reinterpret_cast<const f16x8*>(&woutT[oc * CI + kt * 32 + lk8]);
                acc[c0] = __builtin_amdgcn_mfma_f32_16x16x32_f16(aq[kt], bb, acc[c0], 0, 0, 0);
            }
        }
        #pragma unroll
        for (int c0 = 0; c0 < 4; ++c0)
            #pragma unroll
            for (int j = 0; j < 4; ++j)
                OB[(w * 16 + (l >> 4) * 4 + j) * 132 + cbase + c0 * 16 + lrow] = acc[c0][j];
    }
    __syncthreads();

    const int r  = tid >> 2;
    const int c4 = (tid & 3) * 4;
    #pragma unroll
    for (int q = 0; q < 8; ++q) {
        int col = q * 16 + c4;
        f32x4 v  = *reinterpret_cast<const f32x4*>(&OB[r * 132 + col]);
        f32x4 bb = *reinterpret_cast<const f32x4*>(&bout[ch * 128 + col]);
        f32x4 xv = *reinterpret_cast<const f32x4*>(&x[(size_t)(m0 + r) * CO + ch * 128 + col]);
        f32x4 res;
        #pragma unroll
        for (int e = 0; e < 4; ++e) res[e] = v[e] + bb[e] + xv[e];
        *reinterpret_cast<f32x4*>(&out[(size_t)(m0 + r) * CO + ch * 128 + col]) = res;
    }
}

// ---------------------------------------------------------------------------
extern "C" void kernel_launch(void* const* d_in, const int* in_sizes, int n_in,
                              void* d_out, int out_size, void* d_ws, size_t ws_size,
                              hipStream_t stream) {
    const float* x  = (const float*)d_in[0];
    const float* wt = (const float*)d_in[1];
    const float* bt = (const float*)d_in[2];
    const float* wp = (const float*)d_in[3];
    const float* bp = (const float*)d_in[4];
    const float* wg = (const float*)d_in[5];
    const float* bg = (const float*)d_in[6];
    const float* wo = (const float*)d_in[7];
    const float* bo = (const float*)d_in[8];
    float* out = (float*)d_out;

    char* ws = (char*)d_ws;
    const size_t SZ_PROJT = 384 * 256 * sizeof(f16);
    const size_t SZ_OUTT  = 256 * 128 * sizeof(f16);
    const size_t SZ_MAT   = (size_t)MTOT * CI * sizeof(f16);
    const size_t SZ_ML    = (size_t)MTOT * sizeof(float2);
    const size_t BASE3    = SZ_PROJT + SZ_OUTT;

    f16* wprojT = (f16*)ws;
    f16* woutT  = (f16*)(ws + SZ_PROJT);
    f16* theta  = (f16*)(ws + BASE3);
    f16* phi    = (f16*)(ws + BASE3 + SZ_MAT);
    f16* gt     = (f16*)(ws + BASE3 + 2 * SZ_MAT);
    char* tail  = ws + BASE3 + 3 * SZ_MAT;
    size_t tail_avail = (ws_size > (size_t)(tail - ws)) ? ws_size - (size_t)(tail - ws) : 0;

    int nsplit = 1;
    if (tail_avail >= 5 * (SZ_MAT + SZ_ML)) nsplit = 5;       // 520 blocks ~ 2.03/CU
    else if (tail_avail >= 4 * (SZ_MAT + SZ_ML)) nsplit = 4;

    f16*    Opart = (f16*)tail;
    float2* ml    = (float2*)(tail + (size_t)nsplit * SZ_MAT);

    hipLaunchKernelGGL(prep_weights, dim3(640), dim3(256), 0, stream,
                       wt, wp, wg, wo, wprojT, woutT);
    hipLaunchKernelGGL(proj_gemm, dim3(392, 2), dim3(256), 0, stream,
                       x, wprojT, bt, bp, bg, theta, phi, gt);
    hipLaunchKernelGGL(attn_partial, dim3(B_SZ, NQT, nsplit), dim3(1024), 0, stream,
                       theta, phi, gt, Opart, ml, nsplit, (nsplit > 1) ? 1 : 0);
    hipLaunchKernelGGL(out_proj, dim3(392, 2), dim3(256), 0, stream,
                       Opart, ml, nsplit, woutT, bo, x, out);
}

// Round 15
// 158.816 us; speedup vs baseline: 1.1572x; 1.1572x over previous
//
#include <hip/hip_runtime.h>
#include <hip/hip_bf16.h>
#include <cstdint>
#include <cstddef>

typedef _Float16 f16;
typedef _Float16 f16x8 __attribute__((ext_vector_type(8)));
typedef _Float16 f16x4 __attribute__((ext_vector_type(4)));
typedef float    f32x4 __attribute__((ext_vector_type(4)));
typedef unsigned int u32;

#define B_SZ   8
#define NPOS   3136      // 56*56
#define CIN    256
#define CI     128       // C_INTER
#define CO     256
#define MTOT   (B_SZ*NPOS)   // 25088
#define NT     49            // KV tiles of 64
#define L2E    1.44269504f

union HPack { f16 h[2]; u32 u; };
union HVec8 { u32 u[4]; f16x8 v; };

// async global->LDS, 16B per lane; LDS dest = wave-uniform base + lane*16
__device__ __forceinline__ void async16(const f16* g, f16* l) {
    __builtin_amdgcn_global_load_lds((const __attribute__((address_space(1))) void*)g,
                                     (__attribute__((address_space(3))) void*)l, 16, 0, 0);
}

// ---------------------------------------------------------------------------
// Kernel 0: weight prep — transpose + fp32->fp16
// ---------------------------------------------------------------------------
__global__ void prep_weights(const float* __restrict__ wt, const float* __restrict__ wp,
                             const float* __restrict__ wg, const float* __restrict__ wo,
                             f16* __restrict__ wprojT, f16* __restrict__ woutT) {
    int o = blockIdx.x;
    int k = threadIdx.x;
    if (o < 384) {
        const float* w = (o < 128) ? wt : (o < 256) ? wp : wg;
        int d = o & 127;
        wprojT[o * 256 + k] = (f16)w[k * 128 + d];
    } else {
        int oo = o - 384;           // 0..255
        if (k < 128) woutT[oo * 128 + k] = (f16)wo[k * 256 + oo];
    }
}

// ---------------------------------------------------------------------------
// Kernel 1: fused projection GEMM.  grid (392, 2); theta pre-scaled by
//   log2(e); g^T via swapped mfma. SINGLE 8 KB bounce buffer -> LDS exactly
//   40 KB -> 4 blocks/CU -> all 784 blocks resident (no pipeline drain).
// ---------------------------------------------------------------------------
__launch_bounds__(256)
__global__ void proj_gemm(const float* __restrict__ x, const f16* __restrict__ wprojT,
                          const float* __restrict__ bth, const float* __restrict__ bph,
                          const float* __restrict__ bgg,
                          f16* __restrict__ theta, f16* __restrict__ phi,
                          f16* __restrict__ gt) {
    const int mt  = blockIdx.x;          // 0..391
    const int cy  = blockIdx.y;          // 0..1
    const int m0  = mt * 64;
    const int b   = mt / NT;
    const int n0  = (mt % NT) * 64;
    const int tid = threadIdx.x;
    const int w   = tid >> 6;
    const int l   = tid & 63;
    const int lrow = l & 15;
    const int lk8  = (l >> 4) * 8;

    __shared__ alignas(16) f16 At[64 * 256];   // 32 KB
    __shared__ alignas(16) f16 Bo[64 * 64];    // 8 KB (chunk-XOR swizzled)

    #pragma unroll
    for (int i = 0; i < 16; ++i) {
        int c   = tid + 256 * i;
        int row = c >> 6;
        int col = (c & 63) * 4;
        f32x4 v = *reinterpret_cast<const f32x4*>(&x[(size_t)(m0 + row) * CIN + col]);
        f16x4 t;
        t[0] = (f16)v[0]; t[1] = (f16)v[1]; t[2] = (f16)v[2]; t[3] = (f16)v[3];
        *reinterpret_cast<f16x4*>(&At[row * 256 + (col ^ ((row & 7) << 3))]) = t;
    }
    __syncthreads();

    const int arow = w * 16 + lrow;
    f16x8 af[8];
    #pragma unroll
    for (int kt = 0; kt < 8; ++kt) {
        int kk = kt * 32 + lk8;
        af[kt] = *reinterpret_cast<const f16x8*>(&At[arow * 256 + (kk ^ ((arow & 7) << 3))]);
    }

    for (int cc = 0; cc < 3; ++cc) {
        const int ct = cy * 3 + cc;
        f32x4 acc[4];
        #pragma unroll
        for (int c0 = 0; c0 < 4; ++c0) acc[c0] = (f32x4){0.f, 0.f, 0.f, 0.f};
        const int c0base = ct * 64;
        const bool is_g = (ct >= 4);
        #pragma unroll
        for (int kt = 0; kt < 8; ++kt) {
            int kk = kt * 32 + lk8;
            #pragma unroll
            for (int c0 = 0; c0 < 4; ++c0) {
                int col = c0base + c0 * 16 + lrow;
                f16x8 bb = *reinterpret_cast<const f16x8*>(&wprojT[col * 256 + kk]);
                if (is_g)
                    acc[c0] = __builtin_amdgcn_mfma_f32_16x16x32_f16(bb, af[kt], acc[c0], 0, 0, 0);
                else
                    acc[c0] = __builtin_amdgcn_mfma_f32_16x16x32_f16(af[kt], bb, acc[c0], 0, 0, 0);
            }
        }
        if (!is_g) {
            const float* bv = (ct < 2) ? bth : bph;
            #pragma unroll
            for (int c0 = 0; c0 < 4; ++c0) {
                int d = ((c0base + c0 * 16 + lrow) & 127);
                float bias = bv[d];
                #pragma unroll
                for (int j = 0; j < 4; ++j) {
                    int r = w * 16 + (l >> 4) * 4 + j;
                    float v = acc[c0][j] + bias;
                    if (ct < 2) v *= L2E;
                    Bo[r * 64 + ((c0 * 16 + lrow) ^ ((r & 3) << 4))] = (f16)v;
                }
            }
        } else {
            #pragma unroll
            for (int c0 = 0; c0 < 4; ++c0) {
                #pragma unroll
                for (int j = 0; j < 4; ++j) {
                    int dsub = c0 * 16 + (l >> 4) * 4 + j;
                    int d    = (ct - 4) * 64 + dsub;
                    Bo[dsub * 64 + ((w * 16 + lrow) ^ ((dsub & 3) << 4))] =
                        (f16)(acc[c0][j] + bgg[d]);
                }
            }
        }
        __syncthreads();   // writes visible
        {
            int r   = tid >> 2;
            int cb  = (tid & 3) * 16;
            int cbs = cb ^ ((r & 3) << 4);
            f16x8 v0 = *reinterpret_cast<const f16x8*>(&Bo[r * 64 + cbs]);
            f16x8 v1 = *reinterpret_cast<const f16x8*>(&Bo[r * 64 + cbs + 8]);
            if (!is_g) {
                f16* dst = (ct < 2) ? theta : phi;
                int dbase = (ct & 1) * 64;
                size_t off = ((size_t)b * NPOS + n0 + r) * CI + dbase + cb;
                *reinterpret_cast<f16x8*>(&dst[off])     = v0;
                *reinterpret_cast<f16x8*>(&dst[off + 8]) = v1;
            } else {
                int dglob = (ct - 4) * 64 + r;
                size_t off = ((size_t)b * CI + dglob) * NPOS + n0 + cb;
                *reinterpret_cast<f16x8*>(&gt[off])     = v0;
                *reinterpret_cast<f16x8*>(&gt[off + 8]) = v1;
            }
        }
        __syncthreads();   // Bo free for next col-tile
    }
}

// ---------------------------------------------------------------------------
// Kernel 2: flash attention, KV-split (r12-verbatim pipeline). 512 thr
//   (8 waves), QBLK=128, KVBLK=64, dbuf K/V (1 barrier/tile), gload_lds
//   staging with inverse-swizzled source, t+1 issued at loop top. Swapped
//   QK^T -> S^T in regs; in-register softmax; P repacked via shfl.
//   nsplit=5 -> grid 1000 over 512-block capacity = 97.6% pipeline eff.
// ---------------------------------------------------------------------------
__launch_bounds__(512)
__global__ void attn_partial(const f16* __restrict__ theta, const f16* __restrict__ phi,
                             const f16* __restrict__ gt, f16* __restrict__ Opart,
                             float2* __restrict__ ml, int nsplit, int do_ml) {
    const int b   = blockIdx.x;   // 0..7  (XCD-pinned)
    const int qt  = blockIdx.y;   // 0..24
    const int s   = blockIdx.z;   // 0..nsplit-1
    const int t0  = (NT * s) / nsplit;
    const int t1  = (NT * (s + 1)) / nsplit;
    const int tid = threadIdx.x;
    const int w   = tid >> 6;     // 0..7
    const int l   = tid & 63;
    const int lrow = l & 15;
    const int lk8  = (l >> 4) * 8;

    __shared__ alignas(16) f16 Kt[2][64 * 128];  // 32 KB (swizzled via source)
    __shared__ alignas(16) f16 Vt[2][128 * 64];  // 32 KB

    const f16* thB = theta + (size_t)b * NPOS * CI;
    const f16* phB = phi   + (size_t)b * NPOS * CI;
    const f16* gtB = gt    + (size_t)b * CI * NPOS;

    const int q0  = qt * 128 + w * 16;
    const int qld = min(q0 + lrow, NPOS - 1);

    // Q fragments (B-operand for swapped QK^T)
    f16x8 aq[4];
    #pragma unroll
    for (int kt = 0; kt < 4; ++kt)
        aq[kt] = *reinterpret_cast<const f16x8*>(&thB[(size_t)qld * CI + kt * 32 + lk8]);

    // ---- gload_lds staging geometry ----
    int kch0 = w * 128 + l,      kch1 = kch0 + 64;
    const int krow0 = kch0 >> 4, kcs0 = ((kch0 & 15) ^ (krow0 & 7)) * 8;
    const int krow1 = kch1 >> 4, kcs1 = ((kch1 & 15) ^ (krow1 & 7)) * 8;
    const int vrow0 = kch0 >> 3, vcs0 = ((kch0 & 7) ^ (vrow0 & 7)) * 8;
    const int vrow1 = kch1 >> 3, vcs1 = ((kch1 & 7) ^ (vrow1 & 7)) * 8;
    const int kbase0 = (w * 128) * 8, kbase1 = (w * 128 + 64) * 8;   // f16 units

    f32x4 o[8];
    #pragma unroll
    for (int d0 = 0; d0 < 8; ++d0) o[d0] = (f32x4){0.f, 0.f, 0.f, 0.f};
    float mq = -1e30f;          // running max for q = l&15 (log2 domain)
    float lq = 0.f;             // running denominator for q = l&15

    // P-redistribution lane constants
    const int src0 = ((l & 16) ? 32 : 0) + lrow;   // 32*(g'&1) + q
    const int src1 = src0 + 16;
    const bool selhi = (l >= 32);

    // prologue: stage tile t0 into buf 0
    {
        int kv0 = t0 * 64;
        async16(phB + (size_t)(kv0 + krow0) * CI + kcs0, &Kt[0][kbase0]);
        async16(phB + (size_t)(kv0 + krow1) * CI + kcs1, &Kt[0][kbase1]);
        async16(gtB + (size_t)vrow0 * NPOS + kv0 + vcs0, &Vt[0][kbase0]);
        async16(gtB + (size_t)vrow1 * NPOS + kv0 + vcs1, &Vt[0][kbase1]);
    }
    __syncthreads();
    int cur = 0;

    for (int t = t0; t < t1; ++t) {
        // ---- issue t+1 staging into buf[cur^1]; lands under compute ----
        if (t + 1 < t1) {
            int nv0 = (t + 1) * 64;
            async16(phB + (size_t)(nv0 + krow0) * CI + kcs0, &Kt[cur ^ 1][kbase0]);
            async16(phB + (size_t)(nv0 + krow1) * CI + kcs1, &Kt[cur ^ 1][kbase1]);
            async16(gtB + (size_t)vrow0 * NPOS + nv0 + vcs0, &Vt[cur ^ 1][kbase0]);
            async16(gtB + (size_t)vrow1 * NPOS + nv0 + vcs1, &Vt[cur ^ 1][kbase1]);
        }
        const f16* KT = Kt[cur];
        const f16* VT = Vt[cur];

        // ---- S^T = K Q^T (swapped): q=l&15, kv=c0*16+(l>>4)*4+j ----
        f32x4 sr[4];
        #pragma unroll
        for (int c0 = 0; c0 < 4; ++c0) sr[c0] = (f32x4){0.f, 0.f, 0.f, 0.f};
        __builtin_amdgcn_s_setprio(1);
        #pragma unroll
        for (int kt = 0; kt < 4; ++kt) {
            #pragma unroll
            for (int c0 = 0; c0 < 4; ++c0) {
                int krow = c0 * 16 + lrow;
                f16x8 bk = *reinterpret_cast<const f16x8*>(
                    &KT[krow * 128 + ((kt * 32 + lk8) ^ ((krow & 7) << 3))]);
                sr[c0] = __builtin_amdgcn_mfma_f32_16x16x32_f16(bk, aq[kt], sr[c0], 0, 0, 0);
            }
        }
        __builtin_amdgcn_s_setprio(0);

        // ---- in-register online softmax (lazy max, deferred cross-lane sum) ----
        float m01 = fmaxf(fmaxf(sr[0][0], sr[0][1]), fmaxf(sr[0][2], sr[0][3]));
        float m23 = fmaxf(fmaxf(sr[1][0], sr[1][1]), fmaxf(sr[1][2], sr[1][3]));
        float m45 = fmaxf(fmaxf(sr[2][0], sr[2][1]), fmaxf(sr[2][2], sr[2][3]));
        float m67 = fmaxf(fmaxf(sr[3][0], sr[3][1]), fmaxf(sr[3][2], sr[3][3]));
        float rml = fmaxf(fmaxf(m01, m23), fmaxf(m45, m67));

        if (__any(rml > mq + 8.0f)) {
            float rm = fmaxf(rml, __shfl_xor(rml, 16));
            rm = fmaxf(rm, __shfl_xor(rm, 32));
            float mnew  = fmaxf(mq, rm);
            float scale = __builtin_amdgcn_exp2f(mq - mnew);
            mq = mnew;
            lq *= scale;
            float sc0 = __shfl(scale, (l >> 4) * 4 + 0);
            float sc1 = __shfl(scale, (l >> 4) * 4 + 1);
            float sc2 = __shfl(scale, (l >> 4) * 4 + 2);
            float sc3 = __shfl(scale, (l >> 4) * 4 + 3);
            #pragma unroll
            for (int d0 = 0; d0 < 8; ++d0) {
                o[d0][0] *= sc0; o[d0][1] *= sc1; o[d0][2] *= sc2; o[d0][3] *= sc3;
            }
        }

        float p[4][4];
        #pragma unroll
        for (int c0 = 0; c0 < 4; ++c0)
            #pragma unroll
            for (int j = 0; j < 4; ++j)
                p[c0][j] = __builtin_amdgcn_exp2f(sr[c0][j] - mq);
        {
            float s0 = (p[0][0] + p[0][1]) + (p[0][2] + p[0][3]);
            float s1 = (p[1][0] + p[1][1]) + (p[1][2] + p[1][3]);
            float s2 = (p[2][0] + p[2][1]) + (p[2][2] + p[2][3]);
            float s3 = (p[3][0] + p[3][1]) + (p[3][2] + p[3][3]);
            lq += (s0 + s1) + (s2 + s3);
        }

        // ---- pack P to f16 pairs ----
        u32 wlo[4], whi[4];
        #pragma unroll
        for (int c0 = 0; c0 < 4; ++c0) {
            HPack a, bpk;
            a.h[0]   = (f16)p[c0][0]; a.h[1]   = (f16)p[c0][1];
            bpk.h[0] = (f16)p[c0][2]; bpk.h[1] = (f16)p[c0][3];
            wlo[c0] = a.u; whi[c0] = bpk.u;
        }

        // ---- redistribute to PV A-fragments (registers only) ----
        HVec8 pa0, pa1;
        {
            u32 aL0 = (u32)__shfl((int)wlo[0], src0), aH0 = (u32)__shfl((int)wlo[1], src0);
            u32 aL1 = (u32)__shfl((int)whi[0], src0), aH1 = (u32)__shfl((int)whi[1], src0);
            u32 bL0 = (u32)__shfl((int)wlo[0], src1), bH0 = (u32)__shfl((int)wlo[1], src1);
            u32 bL1 = (u32)__shfl((int)whi[0], src1), bH1 = (u32)__shfl((int)whi[1], src1);
            pa0.u[0] = selhi ? aH0 : aL0;
            pa0.u[1] = selhi ? aH1 : aL1;
            pa0.u[2] = selhi ? bH0 : bL0;
            pa0.u[3] = selhi ? bH1 : bL1;
        }
        {
            u32 aL0 = (u32)__shfl((int)wlo[2], src0), aH0 = (u32)__shfl((int)wlo[3], src0);
            u32 aL1 = (u32)__shfl((int)whi[2], src0), aH1 = (u32)__shfl((int)whi[3], src0);
            u32 bL0 = (u32)__shfl((int)wlo[2], src1), bH0 = (u32)__shfl((int)wlo[3], src1);
            u32 bL1 = (u32)__shfl((int)whi[2], src1), bH1 = (u32)__shfl((int)whi[3], src1);
            pa1.u[0] = selhi ? aH0 : aL0;
            pa1.u[1] = selhi ? aH1 : aL1;
            pa1.u[2] = selhi ? bH0 : bL0;
            pa1.u[3] = selhi ? bH1 : bL1;
        }

        // ---- O += P V (A from registers, B from LDS) ----
        __builtin_amdgcn_s_setprio(1);
        #pragma unroll
        for (int d0 = 0; d0 < 8; ++d0) {
            int vrow = d0 * 16 + lrow;
            f16x8 bv0 = *reinterpret_cast<const f16x8*>(
                &VT[vrow * 64 + ((lk8) ^ ((vrow & 7) << 3))]);
            f16x8 bv1 = *reinterpret_cast<const f16x8*>(
                &VT[vrow * 64 + ((32 + lk8) ^ ((vrow & 7) << 3))]);
            o[d0] = __builtin_amdgcn_mfma_f32_16x16x32_f16(pa0.v, bv0, o[d0], 0, 0, 0);
            o[d0] = __builtin_amdgcn_mfma_f32_16x16x32_f16(pa1.v, bv1, o[d0], 0, 0, 0);
        }
        __builtin_amdgcn_s_setprio(0);

        __syncthreads();   // drains vmcnt (t+1 loads done) + barrier -> visible
        cur ^= 1;
    }

    // ---- epilogue ----
    lq += __shfl_xor(lq, 16);
    lq += __shfl_xor(lq, 32);
    float inv = 1.f / lq;
    float invj[4];
    #pragma unroll
    for (int j = 0; j < 4; ++j)
        invj[j] = __shfl(inv, (l >> 4) * 4 + j);

    #pragma unroll
    for (int j = 0; j < 4; ++j) {
        int qrow = q0 + (l >> 4) * 4 + j;
        if (qrow < NPOS) {
            size_t grow = (size_t)b * NPOS + qrow;
            #pragma unroll
            for (int d0 = 0; d0 < 8; ++d0) {
                int d = d0 * 16 + lrow;
                Opart[((size_t)s * MTOT + grow) * CI + d] = (f16)(o[d0][j] * invj[j]);
            }
        }
    }
    if (do_ml && l < 16 && q0 + l < NPOS) {
        float2 v; v.x = mq; v.y = lq;
        ml[(size_t)s * MTOT + (size_t)b * NPOS + q0 + l] = v;
    }
}

// ---------------------------------------------------------------------------
// Kernel 3: fused merge + out projection, compile-time NSPLIT (keeps the
//   merge weights in registers).  aq = (sum_s wgt_s O_s)/sum_s wgt_s, then
//   out = x + aq @ w_out + b_out.  LDS-bounce coalesced epilogue.
// ---------------------------------------------------------------------------
template <int NS>
__launch_bounds__(256)
__global__ void out_proj(const f16* __restrict__ Opart, const float2* __restrict__ ml,
                         const f16* __restrict__ woutT,
                         const float* __restrict__ bout, const float* __restrict__ x,
                         float* __restrict__ out) {
    const int mt  = blockIdx.x;
    const int ch  = blockIdx.y;
    const int tid = threadIdx.x;
    const int w   = tid >> 6;
    const int l   = tid & 63;
    const int lrow = l & 15;
    const int lk8  = (l >> 4) * 8;
    const int m0   = mt * 64;
    const int row  = m0 + w * 16 + lrow;

    __shared__ alignas(16) float OB[64 * 132];

    f16x8 aq[4];
    if constexpr (NS > 1) {
        float mx[NS], ly[NS];
        #pragma unroll
        for (int s2 = 0; s2 < NS; ++s2) {
            float2 v = ml[(size_t)s2 * MTOT + row];
            mx[s2] = v.x; ly[s2] = v.y;
        }
        float M = mx[0];
        #pragma unroll
        for (int s2 = 1; s2 < NS; ++s2) M = fmaxf(M, mx[s2]);
        float wgt[NS];
        float L = 0.f;
        #pragma unroll
        for (int s2 = 0; s2 < NS; ++s2) {
            wgt[s2] = ly[s2] * __builtin_amdgcn_exp2f(mx[s2] - M);
            L += wgt[s2];
        }
        float invL = 1.f / L;
        #pragma unroll
        for (int s2 = 0; s2 < NS; ++s2) wgt[s2] *= invL;
        #pragma unroll
        for (int kt = 0; kt < 4; ++kt) {
            float acc8[8];
            #pragma unroll
            for (int j = 0; j < 8; ++j) acc8[j] = 0.f;
            #pragma unroll
            for (int s2 = 0; s2 < NS; ++s2) {
                f16x8 v = *reinterpret_cast<const f16x8*>(
                    &Opart[((size_t)s2 * MTOT + row) * CI + kt * 32 + lk8]);
                #pragma unroll
                for (int j = 0; j < 8; ++j) acc8[j] += wgt[s2] * (float)v[j];
            }
            f16x8 q;
            #pragma unroll
            for (int j = 0; j < 8; ++j) q[j] = (f16)acc8[j];
            aq[kt] = q;
        }
    } else {
        #pragma unroll
        for (int kt = 0; kt < 4; ++kt)
            aq[kt] = *reinterpret_cast<const f16x8*>(&Opart[(size_t)row * CI + kt * 32 + lk8]);
    }

    #pragma unroll
    for (int cc = 0; cc < 2; ++cc) {
        const int cbase = cc * 64;
        f32x4 acc[4];
        #pragma unroll
        for (int c0 = 0; c0 < 4; ++c0) acc[c0] = (f32x4){0.f, 0.f, 0.f, 0.f};
        #pragma unroll
        for (int kt = 0; kt < 4; ++kt) {
            #pragma unroll
            for (int c0 = 0; c0 < 4; ++c0) {
                int oc = ch * 128 + cbase + c0 * 16 + lrow;
                f16x8 bb = *reinterpret_cast<const f16x8*>(&woutT[oc * CI + kt * 32 + lk8]);
                acc[c0] = __builtin_amdgcn_mfma_f32_16x16x32_f16(aq[kt], bb, acc[c0], 0, 0, 0);
            }
        }
        #pragma unroll
        for (int c0 = 0; c0 < 4; ++c0)
            #pragma unroll
            for (int j = 0; j < 4; ++j)
                OB[(w * 16 + (l >> 4) * 4 + j) * 132 + cbase + c0 * 16 + lrow] = acc[c0][j];
    }
    __syncthreads();

    const int r  = tid >> 2;
    const int c4 = (tid & 3) * 4;
    #pragma unroll
    for (int q = 0; q < 8; ++q) {
        int col = q * 16 + c4;
        f32x4 v  = *reinterpret_cast<const f32x4*>(&OB[r * 132 + col]);
        f32x4 bb = *reinterpret_cast<const f32x4*>(&bout[ch * 128 + col]);
        f32x4 xv = *reinterpret_cast<const f32x4*>(&x[(size_t)(m0 + r) * CO + ch * 128 + col]);
        f32x4 res;
        #pragma unroll
        for (int e = 0; e < 4; ++e) res[e] = v[e] + bb[e] + xv[e];
        *reinterpret_cast<f32x4*>(&out[(size_t)(m0 + r) * CO + ch * 128 + col]) = res;
    }
}

// ---------------------------------------------------------------------------
extern "C" void kernel_launch(void* const* d_in, const int* in_sizes, int n_in,
                              void* d_out, int out_size, void* d_ws, size_t ws_size,
                              hipStream_t stream) {
    const float* x  = (const float*)d_in[0];
    const float* wt = (const float*)d_in[1];
    const float* bt = (const float*)d_in[2];
    const float* wp = (const float*)d_in[3];
    const float* bp = (const float*)d_in[4];
    const float* wg = (const float*)d_in[5];
    const float* bg = (const float*)d_in[6];
    const float* wo = (const float*)d_in[7];
    const float* bo = (const float*)d_in[8];
    float* out = (float*)d_out;

    char* ws = (char*)d_ws;
    const size_t SZ_PROJT = 384 * 256 * sizeof(f16);
    const size_t SZ_OUTT  = 256 * 128 * sizeof(f16);
    const size_t SZ_MAT   = (size_t)MTOT * CI * sizeof(f16);
    const size_t SZ_ML    = (size_t)MTOT * sizeof(float2);
    const size_t BASE3    = SZ_PROJT + SZ_OUTT;

    f16* wprojT = (f16*)ws;
    f16* woutT  = (f16*)(ws + SZ_PROJT);
    f16* theta  = (f16*)(ws + BASE3);
    f16* phi    = (f16*)(ws + BASE3 + SZ_MAT);
    f16* gt     = (f16*)(ws + BASE3 + 2 * SZ_MAT);
    char* tail  = ws + BASE3 + 3 * SZ_MAT;
    size_t tail_avail = (ws_size > (size_t)(tail - ws)) ? ws_size - (size_t)(tail - ws) : 0;

    int nsplit = 1;
    if (tail_avail >= 5 * (SZ_MAT + SZ_ML)) nsplit = 5;        // grid 1000: 97.6% pipeline eff
    else if (tail_avail >= 4 * (SZ_MAT + SZ_ML)) nsplit = 4;

    f16*    Opart = (f16*)tail;
    float2* ml    = (float2*)(tail + (size_t)nsplit * SZ_MAT);

    hipLaunchKernelGGL(prep_weights, dim3(640), dim3(256), 0, stream,
                       wt, wp, wg, wo, wprojT, woutT);
    hipLaunchKernelGGL(proj_gemm, dim3(392, 2), dim3(256), 0, stream,
                       x, wprojT, bt, bp, bg, theta, phi, gt);
    hipLaunchKernelGGL(attn_partial, dim3(B_SZ, 25, nsplit), dim3(512), 0, stream,
                       theta, phi, gt, Opart, ml, nsplit, (nsplit > 1) ? 1 : 0);
    if (nsplit == 5)
        hipLaunchKernelGGL(out_proj<5>, dim3(392, 2), dim3(256), 0, stream,
                           Opart, ml, woutT, bo, x, out);
    else if (nsplit == 4)
        hipLaunchKernelGGL(out_proj<4>, dim3(392, 2), dim3(256), 0, stream,
                           Opart, ml, woutT, bo, x, out);
    else
        hipLaunchKernelGGL(out_proj<1>, dim3(392, 2), dim3(256), 0, stream,
                           Opart, ml, woutT, bo, x, out);
}

// Round 16
// 121.898 us; speedup vs baseline: 1.5076x; 1.3029x over previous
//
#include <hip/hip_runtime.h>
#include <hip/hip_bf16.h>
#include <cstdint>
#include <cstddef>

typedef _Float16 f16;
typedef _Float16 f16x8 __attribute__((ext_vector_type(8)));
typedef _Float16 f16x4 __attribute__((ext_vector_type(4)));
typedef float    f32x4 __attribute__((ext_vector_type(4)));
typedef unsigned int u32;

#define B_SZ   8
#define NPOS   3136      // 56*56
#define CIN    256
#define CI     128       // C_INTER
#define CO     256
#define MTOT   (B_SZ*NPOS)   // 25088
#define NT     49            // KV tiles of 64
#define L2E    1.44269504f

union HPack { f16 h[2]; u32 u; };
union HVec8 { u32 u[4]; f16x8 v; };

// async global->LDS, 16B per lane; LDS dest = wave-uniform base + lane*16
__device__ __forceinline__ void async16(const f16* g, f16* l) {
    __builtin_amdgcn_global_load_lds((const __attribute__((address_space(1))) void*)g,
                                     (__attribute__((address_space(3))) void*)l, 16, 0, 0);
}

// ---------------------------------------------------------------------------
// Kernel 0: weight prep — transpose + fp32->fp16
// ---------------------------------------------------------------------------
__global__ void prep_weights(const float* __restrict__ wt, const float* __restrict__ wp,
                             const float* __restrict__ wg, const float* __restrict__ wo,
                             f16* __restrict__ wprojT, f16* __restrict__ woutT) {
    int o = blockIdx.x;
    int k = threadIdx.x;
    if (o < 384) {
        const float* w = (o < 128) ? wt : (o < 256) ? wp : wg;
        int d = o & 127;
        wprojT[o * 256 + k] = (f16)w[k * 128 + d];
    } else {
        int oo = o - 384;           // 0..255
        if (k < 128) woutT[oo * 128 + k] = (f16)wo[k * 256 + oo];
    }
}

// ---------------------------------------------------------------------------
// Kernel 1: fused projection GEMM.  grid (392, 2); theta pre-scaled by
//   log2(e); g^T via swapped mfma. After af[8] is in registers the x-tile in
//   At is dead -> At reused to stage each 64-col WEIGHT tile via gload_lds
//   (inverse-swizzled source) so B-fragments come from LDS, not L2.
//   LDS = 40 KB -> 4 blocks/CU.
// ---------------------------------------------------------------------------
__launch_bounds__(256)
__global__ void proj_gemm(const float* __restrict__ x, const f16* __restrict__ wprojT,
                          const float* __restrict__ bth, const float* __restrict__ bph,
                          const float* __restrict__ bgg,
                          f16* __restrict__ theta, f16* __restrict__ phi,
                          f16* __restrict__ gt) {
    const int mt  = blockIdx.x;          // 0..391
    const int cy  = blockIdx.y;          // 0..1
    const int m0  = mt * 64;
    const int b   = mt / NT;
    const int n0  = (mt % NT) * 64;
    const int tid = threadIdx.x;
    const int w   = tid >> 6;
    const int l   = tid & 63;
    const int lrow = l & 15;
    const int lk8  = (l >> 4) * 8;

    __shared__ alignas(16) f16 At[64 * 256];   // 32 KB: x-tile, then weight tiles
    __shared__ alignas(16) f16 Bo[64 * 64];    // 8 KB bounce (chunk-XOR swizzled)

    #pragma unroll
    for (int i = 0; i < 16; ++i) {
        int c   = tid + 256 * i;
        int row = c >> 6;
        int col = (c & 63) * 4;
        f32x4 v = *reinterpret_cast<const f32x4*>(&x[(size_t)(m0 + row) * CIN + col]);
        f16x4 t;
        t[0] = (f16)v[0]; t[1] = (f16)v[1]; t[2] = (f16)v[2]; t[3] = (f16)v[3];
        *reinterpret_cast<f16x4*>(&At[row * 256 + (col ^ ((row & 7) << 3))]) = t;
    }
    __syncthreads();

    const int arow = w * 16 + lrow;
    f16x8 af[8];
    #pragma unroll
    for (int kt = 0; kt < 8; ++kt) {
        int kk = kt * 32 + lk8;
        af[kt] = *reinterpret_cast<const f16x8*>(&At[arow * 256 + (kk ^ ((arow & 7) << 3))]);
    }
    __syncthreads();   // all af reads complete -> At reusable

    for (int cc = 0; cc < 3; ++cc) {
        const int ct = cy * 3 + cc;
        const int c0base = ct * 64;
        const bool is_g = (ct >= 4);

        // ---- stage weight tile (64 cols x 256 k, f16) into At via gload_lds ----
        #pragma unroll
        for (int i = 0; i < 8; ++i) {
            int c2   = tid + 256 * i;        // 0..2047 16B chunks
            int wcol = c2 >> 5;              // 0..63
            int chnk = c2 & 31;              // 0..31
            const f16* src = wprojT + (size_t)(c0base + wcol) * 256
                             + ((chnk * 8) ^ ((wcol & 7) * 8));
            async16(src, &At[c2 * 8]);
        }
        __syncthreads();   // drains vmcnt -> weight tile visible

        f32x4 acc[4];
        #pragma unroll
        for (int c0 = 0; c0 < 4; ++c0) acc[c0] = (f32x4){0.f, 0.f, 0.f, 0.f};
        #pragma unroll
        for (int kt = 0; kt < 8; ++kt) {
            int kk = kt * 32 + lk8;
            #pragma unroll
            for (int c0 = 0; c0 < 4; ++c0) {
                int colsub = c0 * 16 + lrow;
                f16x8 bb = *reinterpret_cast<const f16x8*>(
                    &At[colsub * 256 + (kk ^ ((colsub & 7) << 3))]);
                if (is_g)
                    acc[c0] = __builtin_amdgcn_mfma_f32_16x16x32_f16(bb, af[kt], acc[c0], 0, 0, 0);
                else
                    acc[c0] = __builtin_amdgcn_mfma_f32_16x16x32_f16(af[kt], bb, acc[c0], 0, 0, 0);
            }
        }
        if (!is_g) {
            const float* bv = (ct < 2) ? bth : bph;
            #pragma unroll
            for (int c0 = 0; c0 < 4; ++c0) {
                int d = ((c0base + c0 * 16 + lrow) & 127);
                float bias = bv[d];
                #pragma unroll
                for (int j = 0; j < 4; ++j) {
                    int r = w * 16 + (l >> 4) * 4 + j;
                    float v = acc[c0][j] + bias;
                    if (ct < 2) v *= L2E;
                    Bo[r * 64 + ((c0 * 16 + lrow) ^ ((r & 3) << 4))] = (f16)v;
                }
            }
        } else {
            #pragma unroll
            for (int c0 = 0; c0 < 4; ++c0) {
                #pragma unroll
                for (int j = 0; j < 4; ++j) {
                    int dsub = c0 * 16 + (l >> 4) * 4 + j;
                    int d    = (ct - 4) * 64 + dsub;
                    Bo[dsub * 64 + ((w * 16 + lrow) ^ ((dsub & 3) << 4))] =
                        (f16)(acc[c0][j] + bgg[d]);
                }
            }
        }
        __syncthreads();   // Bo visible; all bb reads of At done
        {
            int r   = tid >> 2;
            int cb  = (tid & 3) * 16;
            int cbs = cb ^ ((r & 3) << 4);
            f16x8 v0 = *reinterpret_cast<const f16x8*>(&Bo[r * 64 + cbs]);
            f16x8 v1 = *reinterpret_cast<const f16x8*>(&Bo[r * 64 + cbs + 8]);
            if (!is_g) {
                f16* dst = (ct < 2) ? theta : phi;
                int dbase = (ct & 1) * 64;
                size_t off = ((size_t)b * NPOS + n0 + r) * CI + dbase + cb;
                *reinterpret_cast<f16x8*>(&dst[off])     = v0;
                *reinterpret_cast<f16x8*>(&dst[off + 8]) = v1;
            } else {
                int dglob = (ct - 4) * 64 + r;
                size_t off = ((size_t)b * CI + dglob) * NPOS + n0 + cb;
                *reinterpret_cast<f16x8*>(&gt[off])     = v0;
                *reinterpret_cast<f16x8*>(&gt[off + 8]) = v1;
            }
        }
        __syncthreads();   // Bo and At free for next col-tile
    }
}

// ---------------------------------------------------------------------------
// Kernel 2: flash attention, KV-split (r15-verbatim: 512 thr, QBLK=128,
//   KVBLK=64, dbuf, gload_lds staging, 1 barrier/tile, in-register softmax,
//   P repacked via shfl; nsplit=5 -> 97.6% pipeline efficiency).
// ---------------------------------------------------------------------------
__launch_bounds__(512)
__global__ void attn_partial(const f16* __restrict__ theta, const f16* __restrict__ phi,
                             const f16* __restrict__ gt, f16* __restrict__ Opart,
                             float2* __restrict__ ml, int nsplit, int do_ml) {
    const int b   = blockIdx.x;   // 0..7  (XCD-pinned)
    const int qt  = blockIdx.y;   // 0..24
    const int s   = blockIdx.z;   // 0..nsplit-1
    const int t0  = (NT * s) / nsplit;
    const int t1  = (NT * (s + 1)) / nsplit;
    const int tid = threadIdx.x;
    const int w   = tid >> 6;     // 0..7
    const int l   = tid & 63;
    const int lrow = l & 15;
    const int lk8  = (l >> 4) * 8;

    __shared__ alignas(16) f16 Kt[2][64 * 128];  // 32 KB (swizzled via source)
    __shared__ alignas(16) f16 Vt[2][128 * 64];  // 32 KB

    const f16* thB = theta + (size_t)b * NPOS * CI;
    const f16* phB = phi   + (size_t)b * NPOS * CI;
    const f16* gtB = gt    + (size_t)b * CI * NPOS;

    const int q0  = qt * 128 + w * 16;
    const int qld = min(q0 + lrow, NPOS - 1);

    f16x8 aq[4];
    #pragma unroll
    for (int kt = 0; kt < 4; ++kt)
        aq[kt] = *reinterpret_cast<const f16x8*>(&thB[(size_t)qld * CI + kt * 32 + lk8]);

    int kch0 = w * 128 + l,      kch1 = kch0 + 64;
    const int krow0 = kch0 >> 4, kcs0 = ((kch0 & 15) ^ (krow0 & 7)) * 8;
    const int krow1 = kch1 >> 4, kcs1 = ((kch1 & 15) ^ (krow1 & 7)) * 8;
    const int vrow0 = kch0 >> 3, vcs0 = ((kch0 & 7) ^ (vrow0 & 7)) * 8;
    const int vrow1 = kch1 >> 3, vcs1 = ((kch1 & 7) ^ (vrow1 & 7)) * 8;
    const int kbase0 = (w * 128) * 8, kbase1 = (w * 128 + 64) * 8;

    f32x4 o[8];
    #pragma unroll
    for (int d0 = 0; d0 < 8; ++d0) o[d0] = (f32x4){0.f, 0.f, 0.f, 0.f};
    float mq = -1e30f;
    float lq = 0.f;

    const int src0 = ((l & 16) ? 32 : 0) + lrow;
    const int src1 = src0 + 16;
    const bool selhi = (l >= 32);

    {
        int kv0 = t0 * 64;
        async16(phB + (size_t)(kv0 + krow0) * CI + kcs0, &Kt[0][kbase0]);
        async16(phB + (size_t)(kv0 + krow1) * CI + kcs1, &Kt[0][kbase1]);
        async16(gtB + (size_t)vrow0 * NPOS + kv0 + vcs0, &Vt[0][kbase0]);
        async16(gtB + (size_t)vrow1 * NPOS + kv0 + vcs1, &Vt[0][kbase1]);
    }
    __syncthreads();
    int cur = 0;

    for (int t = t0; t < t1; ++t) {
        if (t + 1 < t1) {
            int nv0 = (t + 1) * 64;
            async16(phB + (size_t)(nv0 + krow0) * CI + kcs0, &Kt[cur ^ 1][kbase0]);
            async16(phB + (size_t)(nv0 + krow1) * CI + kcs1, &Kt[cur ^ 1][kbase1]);
            async16(gtB + (size_t)vrow0 * NPOS + nv0 + vcs0, &Vt[cur ^ 1][kbase0]);
            async16(gtB + (size_t)vrow1 * NPOS + nv0 + vcs1, &Vt[cur ^ 1][kbase1]);
        }
        const f16* KT = Kt[cur];
        const f16* VT = Vt[cur];

        f32x4 sr[4];
        #pragma unroll
        for (int c0 = 0; c0 < 4; ++c0) sr[c0] = (f32x4){0.f, 0.f, 0.f, 0.f};
        __builtin_amdgcn_s_setprio(1);
        #pragma unroll
        for (int kt = 0; kt < 4; ++kt) {
            #pragma unroll
            for (int c0 = 0; c0 < 4; ++c0) {
                int krow = c0 * 16 + lrow;
                f16x8 bk = *reinterpret_cast<const f16x8*>(
                    &KT[krow * 128 + ((kt * 32 + lk8) ^ ((krow & 7) << 3))]);
                sr[c0] = __builtin_amdgcn_mfma_f32_16x16x32_f16(bk, aq[kt], sr[c0], 0, 0, 0);
            }
        }
        __builtin_amdgcn_s_setprio(0);

        float m01 = fmaxf(fmaxf(sr[0][0], sr[0][1]), fmaxf(sr[0][2], sr[0][3]));
        float m23 = fmaxf(fmaxf(sr[1][0], sr[1][1]), fmaxf(sr[1][2], sr[1][3]));
        float m45 = fmaxf(fmaxf(sr[2][0], sr[2][1]), fmaxf(sr[2][2], sr[2][3]));
        float m67 = fmaxf(fmaxf(sr[3][0], sr[3][1]), fmaxf(sr[3][2], sr[3][3]));
        float rml = fmaxf(fmaxf(m01, m23), fmaxf(m45, m67));

        if (__any(rml > mq + 8.0f)) {
            float rm = fmaxf(rml, __shfl_xor(rml, 16));
            rm = fmaxf(rm, __shfl_xor(rm, 32));
            float mnew  = fmaxf(mq, rm);
            float scale = __builtin_amdgcn_exp2f(mq - mnew);
            mq = mnew;
            lq *= scale;
            float sc0 = __shfl(scale, (l >> 4) * 4 + 0);
            float sc1 = __shfl(scale, (l >> 4) * 4 + 1);
            float sc2 = __shfl(scale, (l >> 4) * 4 + 2);
            float sc3 = __shfl(scale, (l >> 4) * 4 + 3);
            #pragma unroll
            for (int d0 = 0; d0 < 8; ++d0) {
                o[d0][0] *= sc0; o[d0][1] *= sc1; o[d0][2] *= sc2; o[d0][3] *= sc3;
            }
        }

        float p[4][4];
        #pragma unroll
        for (int c0 = 0; c0 < 4; ++c0)
            #pragma unroll
            for (int j = 0; j < 4; ++j)
                p[c0][j] = __builtin_amdgcn_exp2f(sr[c0][j] - mq);
        {
            float s0 = (p[0][0] + p[0][1]) + (p[0][2] + p[0][3]);
            float s1 = (p[1][0] + p[1][1]) + (p[1][2] + p[1][3]);
            float s2 = (p[2][0] + p[2][1]) + (p[2][2] + p[2][3]);
            float s3 = (p[3][0] + p[3][1]) + (p[3][2] + p[3][3]);
            lq += (s0 + s1) + (s2 + s3);
        }

        u32 wlo[4], whi[4];
        #pragma unroll
        for (int c0 = 0; c0 < 4; ++c0) {
            HPack a, bpk;
            a.h[0]   = (f16)p[c0][0]; a.h[1]   = (f16)p[c0][1];
            bpk.h[0] = (f16)p[c0][2]; bpk.h[1] = (f16)p[c0][3];
            wlo[c0] = a.u; whi[c0] = bpk.u;
        }

        HVec8 pa0, pa1;
        {
            u32 aL0 = (u32)__shfl((int)wlo[0], src0), aH0 = (u32)__shfl((int)wlo[1], src0);
            u32 aL1 = (u32)__shfl((int)whi[0], src0), aH1 = (u32)__shfl((int)whi[1], src0);
            u32 bL0 = (u32)__shfl((int)wlo[0], src1), bH0 = (u32)__shfl((int)wlo[1], src1);
            u32 bL1 = (u32)__shfl((int)whi[0], src1), bH1 = (u32)__shfl((int)whi[1], src1);
            pa0.u[0] = selhi ? aH0 : aL0;
            pa0.u[1] = selhi ? aH1 : aL1;
            pa0.u[2] = selhi ? bH0 : bL0;
            pa0.u[3] = selhi ? bH1 : bL1;
        }
        {
            u32 aL0 = (u32)__shfl((int)wlo[2], src0), aH0 = (u32)__shfl((int)wlo[3], src0);
            u32 aL1 = (u32)__shfl((int)whi[2], src0), aH1 = (u32)__shfl((int)whi[3], src0);
            u32 bL0 = (u32)__shfl((int)wlo[2], src1), bH0 = (u32)__shfl((int)wlo[3], src1);
            u32 bL1 = (u32)__shfl((int)whi[2], src1), bH1 = (u32)__shfl((int)whi[3], src1);
            pa1.u[0] = selhi ? aH0 : aL0;
            pa1.u[1] = selhi ? aH1 : aL1;
            pa1.u[2] = selhi ? bH0 : bL0;
            pa1.u[3] = selhi ? bH1 : bL1;
        }

        __builtin_amdgcn_s_setprio(1);
        #pragma unroll
        for (int d0 = 0; d0 < 8; ++d0) {
            int vrow = d0 * 16 + lrow;
            f16x8 bv0 = *reinterpret_cast<const f16x8*>(
                &VT[vrow * 64 + ((lk8) ^ ((vrow & 7) << 3))]);
            f16x8 bv1 = *reinterpret_cast<const f16x8*>(
                &VT[vrow * 64 + ((32 + lk8) ^ ((vrow & 7) << 3))]);
            o[d0] = __builtin_amdgcn_mfma_f32_16x16x32_f16(pa0.v, bv0, o[d0], 0, 0, 0);
            o[d0] = __builtin_amdgcn_mfma_f32_16x16x32_f16(pa1.v, bv1, o[d0], 0, 0, 0);
        }
        __builtin_amdgcn_s_setprio(0);

        __syncthreads();
        cur ^= 1;
    }

    lq += __shfl_xor(lq, 16);
    lq += __shfl_xor(lq, 32);
    float inv = 1.f / lq;
    float invj[4];
    #pragma unroll
    for (int j = 0; j < 4; ++j)
        invj[j] = __shfl(inv, (l >> 4) * 4 + j);

    #pragma unroll
    for (int j = 0; j < 4; ++j) {
        int qrow = q0 + (l >> 4) * 4 + j;
        if (qrow < NPOS) {
            size_t grow = (size_t)b * NPOS + qrow;
            #pragma unroll
            for (int d0 = 0; d0 < 8; ++d0) {
                int d = d0 * 16 + lrow;
                Opart[((size_t)s * MTOT + grow) * CI + d] = (f16)(o[d0][j] * invj[j]);
            }
        }
    }
    if (do_ml && l < 16 && q0 + l < NPOS) {
        float2 v; v.x = mq; v.y = lq;
        ml[(size_t)s * MTOT + (size_t)b * NPOS + q0 + l] = v;
    }
}

// ---------------------------------------------------------------------------
// Kernel 3: fused merge + out projection, SINGLE merge per row.
//   grid (392): block = 64 rows x 256 cols. Phase 1: merge partials once into
//   a swizzled y-LDS tile. Phase 2: both 128-col halves MFMA from registers
//   (aq from y-LDS) with LDS-bounce coalesced stores.
// ---------------------------------------------------------------------------
template <int NS>
__launch_bounds__(256)
__global__ void out_proj(const f16* __restrict__ Opart, const float2* __restrict__ ml,
                         const f16* __restrict__ woutT,
                         const float* __restrict__ bout, const float* __restrict__ x,
                         float* __restrict__ out) {
    const int mt  = blockIdx.x;        // 0..391
    const int tid = threadIdx.x;
    const int w   = tid >> 6;
    const int l   = tid & 63;
    const int lrow = l & 15;
    const int lk8  = (l >> 4) * 8;
    const int m0   = mt * 64;

    __shared__ alignas(16) f16  Y[64 * 128];    // 16 KB, row-swizzled
    __shared__ alignas(16) float OB[64 * 132];  // 33 KB bounce

    // ---- phase 1: merge (once per row) into Y ----
    {
        const int r   = tid >> 2;          // 0..63
        const int dcb = (tid & 3) * 32;    // 0,32,64,96
        const int row = m0 + r;
        if constexpr (NS > 1) {
            float mx[NS], ly[NS];
            #pragma unroll
            for (int s2 = 0; s2 < NS; ++s2) {
                float2 v = ml[(size_t)s2 * MTOT + row];
                mx[s2] = v.x; ly[s2] = v.y;
            }
            float M = mx[0];
            #pragma unroll
            for (int s2 = 1; s2 < NS; ++s2) M = fmaxf(M, mx[s2]);
            float wgt[NS];
            float L = 0.f;
            #pragma unroll
            for (int s2 = 0; s2 < NS; ++s2) {
                wgt[s2] = ly[s2] * __builtin_amdgcn_exp2f(mx[s2] - M);
                L += wgt[s2];
            }
            float invL = 1.f / L;
            #pragma unroll
            for (int s2 = 0; s2 < NS; ++s2) wgt[s2] *= invL;
            #pragma unroll
            for (int q = 0; q < 4; ++q) {
                int dc = dcb + q * 8;
                float acc8[8];
                #pragma unroll
                for (int j = 0; j < 8; ++j) acc8[j] = 0.f;
                #pragma unroll
                for (int s2 = 0; s2 < NS; ++s2) {
                    f16x8 v = *reinterpret_cast<const f16x8*>(
                        &Opart[((size_t)s2 * MTOT + row) * CI + dc]);
                    #pragma unroll
                    for (int j = 0; j < 8; ++j) acc8[j] += wgt[s2] * (float)v[j];
                }
                f16x8 q8;
                #pragma unroll
                for (int j = 0; j < 8; ++j) q8[j] = (f16)acc8[j];
                *reinterpret_cast<f16x8*>(&Y[r * 128 + (dc ^ ((r & 7) * 8))]) = q8;
            }
        } else {
            #pragma unroll
            for (int q = 0; q < 4; ++q) {
                int dc = dcb + q * 8;
                f16x8 v = *reinterpret_cast<const f16x8*>(&Opart[(size_t)row * CI + dc]);
                *reinterpret_cast<f16x8*>(&Y[r * 128 + (dc ^ ((r & 7) * 8))]) = v;
            }
        }
    }
    __syncthreads();

    // ---- phase 2: aq from Y, MFMA both col-halves ----
    const int yrow = w * 16 + lrow;
    f16x8 aq[4];
    #pragma unroll
    for (int kt = 0; kt < 4; ++kt)
        aq[kt] = *reinterpret_cast<const f16x8*>(
            &Y[yrow * 128 + ((kt * 32 + lk8) ^ ((yrow & 7) * 8))]);

    #pragma unroll
    for (int ch = 0; ch < 2; ++ch) {
        #pragma unroll
        for (int cc = 0; cc < 2; ++cc) {
            const int cbase = cc * 64;
            f32x4 acc[4];
            #pragma unroll
            for (int c0 = 0; c0 < 4; ++c0) acc[c0] = (f32x4){0.f, 0.f, 0.f, 0.f};
            #pragma unroll
            for (int kt = 0; kt < 4; ++kt) {
                #pragma unroll
                for (int c0 = 0; c0 < 4; ++c0) {
                    int oc = ch * 128 + cbase + c0 * 16 + lrow;
                    f16x8 bb = *reinterpret_cast<const f16x8*>(&woutT[oc * CI + kt * 32 + lk8]);
                    acc[c0] = __builtin_amdgcn_mfma_f32_16x16x32_f16(aq[kt], bb, acc[c0], 0, 0, 0);
                }
            }
            #pragma unroll
            for (int c0 = 0; c0 < 4; ++c0)
                #pragma unroll
                for (int j = 0; j < 4; ++j)
                    OB[(w * 16 + (l >> 4) * 4 + j) * 132 + cbase + c0 * 16 + lrow] = acc[c0][j];
        }
        __syncthreads();
        {
            const int r  = tid >> 2;
            const int c4 = (tid & 3) * 4;
            #pragma unroll
            for (int q = 0; q < 8; ++q) {
                int col = q * 16 + c4;
                f32x4 v  = *reinterpret_cast<const f32x4*>(&OB[r * 132 + col]);
                f32x4 bb = *reinterpret_cast<const f32x4*>(&bout[ch * 128 + col]);
                f32x4 xv = *reinterpret_cast<const f32x4*>(
                    &x[(size_t)(m0 + r) * CO + ch * 128 + col]);
                f32x4 res;
                #pragma unroll
                for (int e = 0; e < 4; ++e) res[e] = v[e] + bb[e] + xv[e];
                *reinterpret_cast<f32x4*>(&out[(size_t)(m0 + r) * CO + ch * 128 + col]) = res;
            }
        }
        __syncthreads();   // OB free for second half
    }
}

// ---------------------------------------------------------------------------
extern "C" void kernel_launch(void* const* d_in, const int* in_sizes, int n_in,
                              void* d_out, int out_size, void* d_ws, size_t ws_size,
                              hipStream_t stream) {
    const float* x  = (const float*)d_in[0];
    const float* wt = (const float*)d_in[1];
    const float* bt = (const float*)d_in[2];
    const float* wp = (const float*)d_in[3];
    const float* bp = (const float*)d_in[4];
    const float* wg = (const float*)d_in[5];
    const float* bg = (const float*)d_in[6];
    const float* wo = (const float*)d_in[7];
    const float* bo = (const float*)d_in[8];
    float* out = (float*)d_out;

    char* ws = (char*)d_ws;
    const size_t SZ_PROJT = 384 * 256 * sizeof(f16);
    const size_t SZ_OUTT  = 256 * 128 * sizeof(f16);
    const size_t SZ_MAT   = (size_t)MTOT * CI * sizeof(f16);
    const size_t SZ_ML    = (size_t)MTOT * sizeof(float2);
    const size_t BASE3    = SZ_PROJT + SZ_OUTT;

    f16* wprojT = (f16*)ws;
    f16* woutT  = (f16*)(ws + SZ_PROJT);
    f16* theta  = (f16*)(ws + BASE3);
    f16* phi    = (f16*)(ws + BASE3 + SZ_MAT);
    f16* gt     = (f16*)(ws + BASE3 + 2 * SZ_MAT);
    char* tail  = ws + BASE3 + 3 * SZ_MAT;
    size_t tail_avail = (ws_size > (size_t)(tail - ws)) ? ws_size - (size_t)(tail - ws) : 0;

    int nsplit = 1;
    if (tail_avail >= 5 * (SZ_MAT + SZ_ML)) nsplit = 5;        // grid 1000: 97.6% pipeline eff
    else if (tail_avail >= 4 * (SZ_MAT + SZ_ML)) nsplit = 4;

    f16*    Opart = (f16*)tail;
    float2* ml    = (float2*)(tail + (size_t)nsplit * SZ_MAT);

    hipLaunchKernelGGL(prep_weights, dim3(640), dim3(256), 0, stream,
                       wt, wp, wg, wo, wprojT, woutT);
    hipLaunchKernelGGL(proj_gemm, dim3(392, 2), dim3(256), 0, stream,
                       x, wprojT, bt, bp, bg, theta, phi, gt);
    hipLaunchKernelGGL(attn_partial, dim3(B_SZ, 25, nsplit), dim3(512), 0, stream,
                       theta, phi, gt, Opart, ml, nsplit, (nsplit > 1) ? 1 : 0);
    if (nsplit == 5)
        hipLaunchKernelGGL(out_proj<5>, dim3(392), dim3(256), 0, stream,
                           Opart, ml, woutT, bo, x, out);
    else if (nsplit == 4)
        hipLaunchKernelGGL(out_proj<4>, dim3(392), dim3(256), 0, stream,
                           Opart, ml, woutT, bo, x, out);
    else
        hipLaunchKernelGGL(out_proj<1>, dim3(392), dim3(256), 0, stream,
                           Opart, ml, woutT, bo, x, out);
}